// Round 6
// baseline (94.445 us; speedup 1.0000x reference)
//
#include <hip/hip_runtime.h>

#define BATCH 256
#define NCLS  1019
#define GRID  7
#define NOBJ  16
#define PLANE 49              // GRID*GRID
#define NCH   1024            // 5 + NCLS
#define SLAB  (NCH * PLANE)   // 50176 floats per batch = 196*256 = 256 groups of 49 float4
#define NWAVE 16
#define NGRP  8               // groups per wave in K1 (16 waves x 8 = 128 = half the slab)

// ---------------- K1: stream half a slab, fold to 49 partial sumexps ----------------
// Group g = 196 floats = 49 float4. Lane l<49 loads float4 (49g + l); element j of
// that float4 has FIXED position (4l+j) mod 49 for every g (196 % 49 == 0).
// Block (b,h) owns groups h*128 .. h*128+127; wave w takes g = h*128 + w + 16*i.
__global__ __launch_bounds__(1024, 8) void yolo_sumexp_k1(
    const float* __restrict__ outputs,    // [B, 1024, 7, 7]
    float* __restrict__ ws,               // [B*2, 49] partial sumexp (incl. rows 0..4)
    float* __restrict__ out)              // [1] zeroed here for K2
{
    const int blk  = blockIdx.x;
    const int b    = blk >> 1;
    const int h    = blk & 1;
    const int t    = threadIdx.x;
    const int lane = t & 63;
    const int w    = t >> 6;

    if (blk == 0 && t == 0) out[0] = 0.0f;   // K2 runs after K1 in stream order

    __shared__ float s_slot[NWAVE][4 * PLANE];

    const float4* ob4 = (const float4*)(outputs + (size_t)b * SLAB);
    const bool act = lane < PLANE;
    const int  lc  = act ? lane : 0;         // clamp inactive lanes to a safe addr

    const float4* base = ob4 + (size_t)PLANE * (h * 128 + w) + lc;
    float4 v[NGRP];
#pragma unroll
    for (int i = 0; i < NGRP; ++i)
        v[i] = base[(size_t)PLANE * NWAVE * i];   // 8 loads in flight per wave

    float a0 = 0.0f, a1 = 0.0f, a2 = 0.0f, a3 = 0.0f;
#pragma unroll
    for (int i = 0; i < NGRP; ++i) {
        a0 += __expf(v[i].x);
        a1 += __expf(v[i].y);
        a2 += __expf(v[i].z);
        a3 += __expf(v[i].w);
    }
    if (act) {
        float4* dst = (float4*)&s_slot[w][4 * lc];   // 16B-aligned
        *dst = make_float4(a0, a1, a2, a3);
    }
    __syncthreads();

    // fold 16x196 slot partials -> 49 position sums; write disjoint ws slice
    if (w == 0 && lane < PLANE) {
        float s = 0.0f;
#pragma unroll
        for (int ww = 0; ww < NWAVE; ++ww) {
#pragma unroll
            for (int k = 0; k < 4; ++k)
                s += s_slot[ww][lane + PLANE * k];   // slots {p, p+49, p+98, p+147}
        }
        ws[(size_t)blk * PLANE + lane] = s;
    }
}

// ---------------- K2: L3-hot epilogue, one block per batch ----------------
__global__ __launch_bounds__(128) void yolo_loss_k2(
    const float* __restrict__ outputs,
    const float* __restrict__ boxes,      // [B, 16, 4]
    const int*   __restrict__ labels,     // [B, 16]  (1..C)
    const int*   __restrict__ coords,     // [B, 16, 2] (x, y)
    const float* __restrict__ obj_matrix, // [B, 49]
    const float* __restrict__ ws,         // [B*2, 49]
    float* __restrict__ out)              // [1]
{
    const int b    = blockIdx.x;
    const int t    = threadIdx.x;
    const int lane = t & 63;
    const int w    = t >> 6;

    __shared__ float s_red;
    __shared__ int   s_pos[NOBJ];
    __shared__ int   s_cl[NOBJ];

    const float* ob = outputs + (size_t)b * SLAB;

    if (t == 0) s_red = 0.0f;
    if (t < NOBJ) {
        int x = coords[(b * NOBJ + t) * 2 + 0];
        int y = coords[(b * NOBJ + t) * 2 + 1];
        s_pos[t] = y * GRID + x;
        s_cl[t]  = labels[b * NOBJ + t] - 1;
    }
    __syncthreads();

    // objectness CE (wave 0)
    if (w == 0) {
        float l = (lane < PLANE) ? ob[lane] : 0.0f;
        float s = (lane < PLANE) ? __expf(l) : 0.0f;
#pragma unroll
        for (int off = 32; off > 0; off >>= 1)
            s += __shfl_xor(s, off, 64);
        float lse = __logf(s);
        float mm = (lane < PLANE) ? obj_matrix[b * PLANE + lane] : 0.0f;
        float contrib = (lane < PLANE) ? -mm * (l - lse) : 0.0f;
#pragma unroll
        for (int off = 32; off > 0; off >>= 1)
            contrib += __shfl_xor(contrib, off, 64);
        if (lane == 0) atomicAdd(&s_red, contrib);
    }

    // bb MSE (wave 1)
    if (w == 1) {
        int o = lane >> 2, k = lane & 3;   // 64 lanes = 16 objects x 4 coords
        float pred = ob[(size_t)(1 + k) * PLANE + s_pos[o]];
        float tb   = boxes[(b * NOBJ + o) * 4 + k];
        float tgt  = rintf(tb * (10.0f / 448.0f)) * 0.1f;  // round-half-even
        float d    = tgt - pred;
        float sq   = d * d;
#pragma unroll
        for (int off = 32; off > 0; off >>= 1)
            sq += __shfl_xor(sq, off, 64);
        if (lane == 0) atomicAdd(&s_red, sq);
    }
    __syncthreads();

    // class CE (wave 0, lanes 0..15): combine the two half-slab partials,
    // subtract the obj+bb rows' exp contribution at the object position.
    if (w == 0 && lane < NOBJ) {
        int p = s_pos[lane];
        float se = ws[(size_t)(b * 2) * PLANE + p] + ws[(size_t)(b * 2 + 1) * PLANE + p];
        float corr = 0.0f;
#pragma unroll
        for (int r = 0; r < 5; ++r)
            corr += __expf(ob[r * PLANE + p]);
        float tl = ob[(size_t)(5 + s_cl[lane]) * PLANE + p];  // L2/L3 hit
        float ce = __logf(se - corr) - tl;
        atomicAdd(&s_red, ce);
    }
    __syncthreads();

    if (t == 0) atomicAdd(out, s_red * (1.0f / (float)BATCH));
}

extern "C" void kernel_launch(void* const* d_in, const int* in_sizes, int n_in,
                              void* d_out, int out_size, void* d_ws, size_t ws_size,
                              hipStream_t stream) {
    const float* outputs    = (const float*)d_in[0];
    const float* boxes      = (const float*)d_in[1];
    const int*   labels     = (const int*)d_in[2];
    const int*   coords     = (const int*)d_in[3];
    const float* obj_matrix = (const float*)d_in[4];
    float* out = (float*)d_out;
    float* ws  = (float*)d_ws;   // needs BATCH*2*49*4 = 100 KB

    yolo_sumexp_k1<<<BATCH * 2, 1024, 0, stream>>>(outputs, ws, out);
    yolo_loss_k2<<<BATCH, 128, 0, stream>>>(outputs, boxes, labels, coords,
                                            obj_matrix, ws, out);
}